// Round 1
// baseline (733.124 us; speedup 1.0000x reference)
//
#include <hip/hip_runtime.h>

typedef unsigned short u16;
typedef __bf16 bf16x8 __attribute__((ext_vector_type(8)));
typedef u16 u16x8 __attribute__((ext_vector_type(8)));
typedef float f32x4 __attribute__((ext_vector_type(4)));

#define B_  8
#define N_  4096
#define D_  32
#define CV_ 256

static __device__ __forceinline__ u16 f2bf(float x) {
    union { float f; unsigned int u; } v; v.f = x;
    unsigned int r = (v.u + 0x7FFFu + ((v.u >> 16) & 1u)) >> 16;
    return (u16)r;
}

// ---------------- projection kernel ----------------
// grid = B * (N/64) = 512 blocks, 256 threads.
// f = Wf q + bf  -> fbuf [B][N][32]  (Q rows, bf16)
// g = Wg kv + bg -> gbuf [B][N][32]  (K rows, bf16)
// h = Wh kv + bh -> hbuf [B][256][N] (V^T, bf16)  -- natural [c][n] layout
__global__ __launch_bounds__(256, 2)
void proj_kernel(const float* __restrict__ q, const float* __restrict__ kv,
                 const float* __restrict__ Wf, const float* __restrict__ pbf,
                 const float* __restrict__ Wg, const float* __restrict__ pbg,
                 const float* __restrict__ Wh, const float* __restrict__ pbh,
                 u16* __restrict__ fbuf, u16* __restrict__ gbuf, u16* __restrict__ hbuf)
{
    __shared__ float tile[256][64];          // 64 KB: [channel][pixel]
    const int b    = blockIdx.x >> 6;
    const int n0   = (blockIdx.x & 63) * 64;
    const int t    = threadIdx.x;
    const int w    = t >> 6;                 // wave id 0..3
    const int lane = t & 63;                 // pixel index

    const size_t bbase = (size_t)b * CV_ * N_;

    // ---- load q tile (coalesced float4)
    for (int k = 0; k < 16; k++) {
        int c = k * 16 + (t >> 4);
        int j = (t & 15) * 4;
        float4 v = *(const float4*)(q + bbase + (size_t)c * N_ + n0 + j);
        tile[c][j] = v.x; tile[c][j+1] = v.y; tile[c][j+2] = v.z; tile[c][j+3] = v.w;
    }
    __syncthreads();
    // ---- f: wave w owns att-channels [8w, 8w+8)
    {
        float acc[8];
        for (int k = 0; k < 8; k++) acc[k] = pbf[w*8 + k];
        for (int c = 0; c < 256; c++) {
            float v = tile[c][lane];
            for (int k = 0; k < 8; k++) acc[k] += Wf[(w*8 + k)*256 + c] * v;
        }
        u16x8 o;
        for (int k = 0; k < 8; k++) o[k] = f2bf(acc[k]);
        *(u16x8*)&fbuf[((size_t)b*N_ + n0 + lane)*D_ + w*8] = o;
    }
    __syncthreads();
    // ---- load kv tile
    for (int k = 0; k < 16; k++) {
        int c = k * 16 + (t >> 4);
        int j = (t & 15) * 4;
        float4 v = *(const float4*)(kv + bbase + (size_t)c * N_ + n0 + j);
        tile[c][j] = v.x; tile[c][j+1] = v.y; tile[c][j+2] = v.z; tile[c][j+3] = v.w;
    }
    __syncthreads();
    // ---- g
    {
        float acc[8];
        for (int k = 0; k < 8; k++) acc[k] = pbg[w*8 + k];
        for (int c = 0; c < 256; c++) {
            float v = tile[c][lane];
            for (int k = 0; k < 8; k++) acc[k] += Wg[(w*8 + k)*256 + c] * v;
        }
        u16x8 o;
        for (int k = 0; k < 8; k++) o[k] = f2bf(acc[k]);
        *(u16x8*)&gbuf[((size_t)b*N_ + n0 + lane)*D_ + w*8] = o;
    }
    // ---- h: wave w owns out-channels [64w, 64w+64)
    for (int ch = 0; ch < 8; ch++) {
        float acc[8];
        for (int k = 0; k < 8; k++) acc[k] = pbh[w*64 + ch*8 + k];
        for (int c = 0; c < 256; c++) {
            float v = tile[c][lane];
            for (int k = 0; k < 8; k++) acc[k] += Wh[(w*64 + ch*8 + k)*256 + c] * v;
        }
        for (int k = 0; k < 8; k++)
            hbuf[((size_t)b*CV_ + w*64 + ch*8 + k)*N_ + n0 + lane] = f2bf(acc[k]);
    }
}

// ---------------- flash attention kernel ----------------
// grid = B * (N/128) = 256 blocks, 256 threads (4 waves).
// Each wave owns 32 q-rows (two 16-row subtiles). KV tiled by 64.
__global__ __launch_bounds__(256, 1)
void attn_kernel(const u16* __restrict__ fbuf, const u16* __restrict__ gbuf,
                 const u16* __restrict__ hbuf, const float* __restrict__ kv,
                 const float* __restrict__ gamma_p, float* __restrict__ out)
{
    __shared__ __align__(16) u16 K_lds[64][40];    // [kv][d], pad 32->40 (80B rows)
    __shared__ __align__(16) u16 V_lds[256][72];   // [c][kv], pad 64->72 (144B rows)
    __shared__ __align__(16) u16 P_lds[4][32][72]; // per-wave P [qrow][kv]

    const int b  = blockIdx.x >> 5;
    const int q0 = (blockIdx.x & 31) * 128;
    const int t  = threadIdx.x;
    const int w  = t >> 6;
    const int l  = t & 63;
    const int lg = l >> 4;
    const int lc = l & 15;

    const f32x4 zf = {0.f, 0.f, 0.f, 0.f};

    // Q fragments: rows q0 + w*32 + qt*16 + lc, k = lg*8..+8
    bf16x8 qf[2];
    for (int qt = 0; qt < 2; qt++)
        qf[qt] = *(const bf16x8*)&fbuf[((size_t)b*N_ + q0 + w*32 + qt*16 + lc)*D_ + lg*8];

    f32x4 o_acc[2][16];
    for (int qt = 0; qt < 2; qt++) for (int ct = 0; ct < 16; ct++) o_acc[qt][ct] = zf;
    float m_r[2][4], l_r[2][4];
    for (int qt = 0; qt < 2; qt++) for (int r = 0; r < 4; r++) { m_r[qt][r] = -1e30f; l_r[qt][r] = 0.f; }

    const u16* gb = gbuf + (size_t)b * N_ * D_;
    const u16* hb = hbuf + (size_t)b * CV_ * N_;

    for (int kt = 0; kt < 64; kt++) {
        const int kv0 = kt * 64;
        // stage K tile [64][32]
        {
            int m = t >> 2, d8 = (t & 3) * 8;
            *(bf16x8*)&K_lds[m][d8] = *(const bf16x8*)(gb + (size_t)(kv0 + m)*D_ + d8);
        }
        // stage V tile [256 c][64 kv] from h^T (rows contiguous in n)
        for (int k2 = 0; k2 < 8; k2++) {
            int cc = t + 256*k2;
            int c = cc >> 3, m8 = (cc & 7) * 8;
            *(bf16x8*)&V_lds[c][m8] = *(const bf16x8*)(hb + (size_t)c*N_ + kv0 + m8);
        }
        __syncthreads();

        // ---- S = Q K^T : per qt, 4 fragments of 16 kv-cols
        f32x4 s[2][4];
        for (int mt = 0; mt < 4; mt++) {
            bf16x8 kf = *(const bf16x8*)&K_lds[mt*16 + lc][lg*8];
            for (int qt = 0; qt < 2; qt++)
                s[qt][mt] = __builtin_amdgcn_mfma_f32_16x16x32_bf16(qf[qt], kf, zf, 0, 0, 0);
        }

        // ---- online softmax. Row r_loc = qt*16 + lg*4 + r lives in the 16 lanes of group lg.
        float fac[2][4];
        for (int qt = 0; qt < 2; qt++) {
            for (int r = 0; r < 4; r++) {
                float mx = fmaxf(fmaxf(s[qt][0][r], s[qt][1][r]), fmaxf(s[qt][2][r], s[qt][3][r]));
                mx = fmaxf(mx, __shfl_xor(mx, 1));
                mx = fmaxf(mx, __shfl_xor(mx, 2));
                mx = fmaxf(mx, __shfl_xor(mx, 4));
                mx = fmaxf(mx, __shfl_xor(mx, 8));
                float mn = fmaxf(m_r[qt][r], mx);
                fac[qt][r] = __expf(m_r[qt][r] - mn);
                m_r[qt][r] = mn;
                float ps = 0.f;
                for (int mt = 0; mt < 4; mt++) {
                    float p = __expf(s[qt][mt][r] - mn);
                    s[qt][mt][r] = p;
                    ps += p;
                }
                ps += __shfl_xor(ps, 1);
                ps += __shfl_xor(ps, 2);
                ps += __shfl_xor(ps, 4);
                ps += __shfl_xor(ps, 8);
                l_r[qt][r] = l_r[qt][r]*fac[qt][r] + ps;
            }
        }

        // ---- P -> LDS (bf16); layout [qrow][kv]
        for (int qt = 0; qt < 2; qt++)
            for (int mt = 0; mt < 4; mt++)
                for (int r = 0; r < 4; r++)
                    P_lds[w][qt*16 + lg*4 + r][mt*16 + lc] = f2bf(s[qt][mt][r]);

        // ---- rescale O accumulator
        for (int qt = 0; qt < 2; qt++)
            for (int ct = 0; ct < 16; ct++)
                for (int r = 0; r < 4; r++)
                    o_acc[qt][ct][r] *= fac[qt][r];

        // ---- O += P V  (A and B fragments share the same k-mapping -> layout-proof)
        for (int kh = 0; kh < 2; kh++) {
            bf16x8 pf[2];
            for (int qt = 0; qt < 2; qt++)
                pf[qt] = *(const bf16x8*)&P_lds[w][qt*16 + lc][kh*32 + lg*8];
            for (int ct = 0; ct < 16; ct++) {
                bf16x8 vf = *(const bf16x8*)&V_lds[ct*16 + lc][kh*32 + lg*8];
                for (int qt = 0; qt < 2; qt++)
                    o_acc[qt][ct] = __builtin_amdgcn_mfma_f32_16x16x32_bf16(pf[qt], vf, o_acc[qt][ct], 0, 0, 0);
            }
        }
        __syncthreads();
    }

    // ---- epilogue: out[b][c][n] = gamma * O[n][c] / l[n] + kv[b][c][n]
    const float g = gamma_p[0];
    float inv[2][4];
    for (int qt = 0; qt < 2; qt++) for (int r = 0; r < 4; r++) inv[qt][r] = g / l_r[qt][r];

    float* o_tr = (float*)&V_lds[0][0];    // reuse as [32][129] floats (16512 B)
    for (int cc = 0; cc < 8; cc++) {
        __syncthreads();
        for (int ci = 0; ci < 2; ci++) {
            int ct = cc*2 + ci;
            for (int qt = 0; qt < 2; qt++)
                for (int r = 0; r < 4; r++) {
                    int c_loc = ci*16 + lc;
                    int n_loc = w*32 + qt*16 + lg*4 + r;
                    o_tr[c_loc*129 + n_loc] = o_acc[qt][ct][r] * inv[qt][r];
                }
        }
        __syncthreads();
        int c_loc = t >> 3, seg = t & 7;
        int c = cc*32 + c_loc;
        size_t base = ((size_t)b*CV_ + c)*N_ + q0 + seg*16;
        for (int u = 0; u < 4; u++) {
            float4 kvv = *(const float4*)(kv + base + u*4);
            float4 res;
            res.x = o_tr[c_loc*129 + seg*16 + u*4 + 0] + kvv.x;
            res.y = o_tr[c_loc*129 + seg*16 + u*4 + 1] + kvv.y;
            res.z = o_tr[c_loc*129 + seg*16 + u*4 + 2] + kvv.z;
            res.w = o_tr[c_loc*129 + seg*16 + u*4 + 3] + kvv.w;
            *(float4*)(out + base + u*4) = res;
        }
    }
}

extern "C" void kernel_launch(void* const* d_in, const int* in_sizes, int n_in,
                              void* d_out, int out_size, void* d_ws, size_t ws_size,
                              hipStream_t stream)
{
    const float* q     = (const float*)d_in[0];
    const float* kv    = (const float*)d_in[1];
    const float* Wf    = (const float*)d_in[2];
    const float* pbf   = (const float*)d_in[3];
    const float* Wg    = (const float*)d_in[4];
    const float* pbg   = (const float*)d_in[5];
    const float* Wh    = (const float*)d_in[6];
    const float* pbh   = (const float*)d_in[7];
    const float* gamma = (const float*)d_in[8];
    float* out = (float*)d_out;

    // workspace layout (bf16): fbuf 2MB | gbuf 2MB | hbuf 16MB  (20MB total)
    u16* fbuf = (u16*)d_ws;
    u16* gbuf = fbuf + (size_t)B_ * N_ * D_;
    u16* hbuf = gbuf + (size_t)B_ * N_ * D_;

    proj_kernel<<<dim3(512), dim3(256), 0, stream>>>(q, kv, Wf, pbf, Wg, pbg, Wh, pbh,
                                                     fbuf, gbuf, hbuf);
    attn_kernel<<<dim3(256), dim3(256), 0, stream>>>(fbuf, gbuf, hbuf, kv, gamma, out);
}

// Round 2
// 272.966 us; speedup vs baseline: 2.6858x; 2.6858x over previous
//
#include <hip/hip_runtime.h>

typedef unsigned short u16;
typedef __bf16 bf16x8 __attribute__((ext_vector_type(8)));
typedef float f32x4 __attribute__((ext_vector_type(4)));

#define B_  8
#define N_  4096
#define D_  32
#define CV_ 256

#define MFMA __builtin_amdgcn_mfma_f32_16x16x32_bf16

static __device__ __forceinline__ u16 f2bf(float x) {
    union { float f; unsigned int u; } v; v.f = x;
    unsigned int r = (v.u + 0x7FFFu + ((v.u >> 16) & 1u)) >> 16;
    return (u16)r;
}

static __device__ __forceinline__ void gload16(const u16* g, u16* l) {
    __builtin_amdgcn_global_load_lds(
        (const __attribute__((address_space(1))) unsigned int*)g,
        (__attribute__((address_space(3))) unsigned int*)l, 16, 0, 0);
}

// ---------------- W convert kernel: f32 -> bf16, row-major [out][in] ----------------
__global__ void wcvt_kernel(const float* __restrict__ Wf, const float* __restrict__ Wg,
                            const float* __restrict__ Wh,
                            u16* __restrict__ wfb, u16* __restrict__ wgb, u16* __restrict__ whb)
{
    int i = (blockIdx.x * 256 + threadIdx.x) * 4;   // 81920 f32 total, grid 80x256
    const float* src; u16* dst;
    if (i < 8192)       { src = Wf + i;         dst = wfb + i; }
    else if (i < 16384) { src = Wg + i - 8192;  dst = wgb + i - 8192; }
    else                { src = Wh + i - 16384; dst = whb + i - 16384; }
    float4 v = *(const float4*)src;
    ushort4 o; o.x = f2bf(v.x); o.y = f2bf(v.y); o.z = f2bf(v.z); o.w = f2bf(v.w);
    *(ushort4*)dst = o;
}

// ---------------- projection kernel (MFMA) ----------------
// grid = 512 (b = blk&7, n0 = (blk>>3)*64), 512 threads (8 waves).
// xT tiles [n=64][k=256] bf16, k-chunk XOR-swizzled: chunk' = chunk ^ (n&7).
// waves 0-3: f (n-chunk w). waves 4-7: g (n-chunk w&3). all waves: h c-stripe w*32.
__global__ __launch_bounds__(512, 4)
void proj_kernel(const float* __restrict__ q, const float* __restrict__ kv,
                 const u16* __restrict__ wfb, const float* __restrict__ pbf,
                 const u16* __restrict__ wgb, const float* __restrict__ pbg,
                 const u16* __restrict__ whb, const float* __restrict__ pbh,
                 u16* __restrict__ fbuf, u16* __restrict__ gbuf, u16* __restrict__ hbuf)
{
    __shared__ __align__(16) u16 xq[64][256];   // 32 KB
    __shared__ __align__(16) u16 xk[64][256];   // 32 KB
    const int b  = blockIdx.x & 7;
    const int n0 = (blockIdx.x >> 3) * 64;
    const int t  = threadIdx.x;
    const int w  = t >> 6, lane = t & 63, lg = lane >> 4, lc = lane & 15;
    const size_t bb = (size_t)b * CV_ * N_;
    const f32x4 zf = {0.f, 0.f, 0.f, 0.f};

    // ---- stage q,kv tiles transposed -> [n][k] bf16 with chunk swizzle
    {
        int n = t & 63, cg = t >> 6;
        for (int p = 0; p < 16; p++) {
            int c = (p * 8 + cg) * 2;
            const float* qp = q  + bb + (size_t)c * N_ + n0 + n;
            const float* kp = kv + bb + (size_t)c * N_ + n0 + n;
            float q0v = qp[0], q1v = qp[N_];
            float k0v = kp[0], k1v = kp[N_];
            int idx = (((c >> 3) ^ (n & 7)) * 8) + (c & 7);
            *(unsigned*)&xq[n][idx] = (unsigned)f2bf(q0v) | ((unsigned)f2bf(q1v) << 16);
            *(unsigned*)&xk[n][idx] = (unsigned)f2bf(k0v) | ((unsigned)f2bf(k1v) << 16);
        }
    }
    __syncthreads();

    // ---- f (waves 0-3) / g (waves 4-7): D[n][att] = x^T W^T
    {
        const u16*  wsel = (w < 4) ? wfb : wgb;
        const float* bsel = (w < 4) ? pbf : pbg;
        u16*  osel = (w < 4) ? fbuf : gbuf;
        const u16 (*xs)[256] = (w < 4) ? (const u16(*)[256])xq : (const u16(*)[256])xk;
        const int nch = w & 3;
        f32x4 acc[2] = {zf, zf};
#pragma unroll
        for (int kk = 0; kk < 8; kk++) {
            bf16x8 a = *(const bf16x8*)&xs[nch*16 + lc][((kk*4 + lg) ^ (lc & 7)) * 8];
#pragma unroll
            for (int bt = 0; bt < 2; bt++) {
                bf16x8 bw = *(const bf16x8*)&wsel[(size_t)(bt*16 + lc) * 256 + kk*32 + lg*8];
                acc[bt] = MFMA(a, bw, acc[bt], 0, 0, 0);
            }
        }
#pragma unroll
        for (int bt = 0; bt < 2; bt++) {
            float bias = bsel[bt*16 + lc];
#pragma unroll
            for (int r = 0; r < 4; r++) {
                int n = n0 + nch*16 + lg*4 + r;
                osel[((size_t)b * N_ + n) * D_ + bt*16 + lc] = f2bf(acc[bt][r] + bias);
            }
        }
    }

    // ---- h (all waves): D[c][n] = Wh kv, c-stripe = w*32
    {
        const int cw = w * 32;
        f32x4 acch[2][4];
#pragma unroll
        for (int ct = 0; ct < 2; ct++)
#pragma unroll
            for (int nt = 0; nt < 4; nt++) acch[ct][nt] = zf;
#pragma unroll
        for (int kk = 0; kk < 8; kk++) {
            bf16x8 ah[2];
#pragma unroll
            for (int ct = 0; ct < 2; ct++)
                ah[ct] = *(const bf16x8*)&whb[(size_t)(cw + ct*16 + lc) * 256 + kk*32 + lg*8];
#pragma unroll
            for (int nt = 0; nt < 4; nt++) {
                bf16x8 bx = *(const bf16x8*)&xk[nt*16 + lc][((kk*4 + lg) ^ (lc & 7)) * 8];
#pragma unroll
                for (int ct = 0; ct < 2; ct++)
                    acch[ct][nt] = MFMA(ah[ct], bx, acch[ct][nt], 0, 0, 0);
            }
        }
#pragma unroll
        for (int ct = 0; ct < 2; ct++)
#pragma unroll
            for (int r = 0; r < 4; r++) {
                int c = cw + ct*16 + lg*4 + r;
                float bias = pbh[c];
                u16* hrow = hbuf + ((size_t)b * CV_ + c) * N_ + n0;
                int sw = (c & 7) << 3;
#pragma unroll
                for (int nt = 0; nt < 4; nt++) {
                    int nl = nt*16 + lc;
                    hrow[nl ^ sw] = f2bf(acch[ct][nt][r] + bias);
                }
            }
    }
}

// ---------------- flash attention kernel ----------------
// grid 256 (b = blk&7, q0 = (blk>>3)*128), 512 threads = 8 waves.
// wave: qw = w&3 (32 q-rows: q0+qw*32, qt=0/1), ch = w>>2 (c-half: ct 8 of 16).
// K/V double-buffered via global_load_lds; V columns XOR-swizzled in hbuf.
__global__ __launch_bounds__(512, 2)
void attn_kernel(const u16* __restrict__ fbuf, const u16* __restrict__ gbuf,
                 const u16* __restrict__ hbuf, const float* __restrict__ kvp,
                 const float* __restrict__ gamma_p, float* __restrict__ out)
{
    __shared__ __align__(16) u16 K_lds[2][64][32];    // 8 KB
    __shared__ __align__(16) u16 V_lds[2][256][64];   // 64 KB (rows swizzled by (c&7)<<3)
    __shared__ __align__(16) u16 P_lds[4][32][72];    // 18.4 KB, shared by wave pairs

    const int b  = blockIdx.x & 7;
    const int q0 = (blockIdx.x >> 3) * 128;
    const int t  = threadIdx.x;
    const int w  = t >> 6;
    const int lane = t & 63;
    const int lg = lane >> 4, lc = lane & 15;
    const int qw = w & 3, ch = w >> 2;

    const f32x4 zf = {0.f, 0.f, 0.f, 0.f};
    const u16* gb = gbuf + (size_t)b * N_ * D_;
    const u16* hb = hbuf + (size_t)b * CV_ * N_;

    // Q fragments
    bf16x8 qf[2];
#pragma unroll
    for (int qt = 0; qt < 2; qt++)
        qf[qt] = *(const bf16x8*)&fbuf[((size_t)b*N_ + q0 + qw*32 + qt*16 + lc) * D_ + lg*8];

    f32x4 o_acc[2][8];
#pragma unroll
    for (int qt = 0; qt < 2; qt++)
#pragma unroll
        for (int ct = 0; ct < 8; ct++) o_acc[qt][ct] = zf;
    float m_r[2][4], l_r[2][4];
#pragma unroll
    for (int qt = 0; qt < 2; qt++)
#pragma unroll
        for (int r = 0; r < 4; r++) { m_r[qt][r] = -1e30f; l_r[qt][r] = 0.f; }

    auto stageV = [&](int nb, int kt) {
        const int kv0 = kt * 64;
#pragma unroll
        for (int j = 0; j < 4; j++) {
            int c = j*64 + w*8 + (lane >> 3);
            const u16* g = hb + (size_t)c * N_ + kv0 + (lane & 7) * 8;
            u16* l = (u16*)((char*)&V_lds[nb][0][0] + j*8192 + w*1024);
            gload16(g, l);
        }
    };
    auto stageK = [&](int nb, int kt) {
        if (w < 4) {
            const int kv0 = kt * 64;
            int m = w*16 + (lane >> 2);
            const u16* g = gb + (size_t)(kv0 + m) * D_ + (lane & 3) * 8;
            u16* l = (u16*)((char*)&K_lds[nb][0][0] + w*1024);
            gload16(g, l);
        }
    };

    stageV(0, 0); stageK(0, 0);
    __syncthreads();

    for (int kt = 0; kt < 64; kt++) {
        const int cur = kt & 1;
        if (kt < 63) { stageV(cur ^ 1, kt + 1); stageK(cur ^ 1, kt + 1); }

        // ---- S = Q K^T
        f32x4 s[2][4];
        __builtin_amdgcn_s_setprio(1);
#pragma unroll
        for (int mt = 0; mt < 4; mt++) {
            bf16x8 kf = *(const bf16x8*)&K_lds[cur][mt*16 + lc][lg*8];
            s[0][mt] = MFMA(qf[0], kf, zf, 0, 0, 0);
            s[1][mt] = MFMA(qf[1], kf, zf, 0, 0, 0);
        }
        __builtin_amdgcn_s_setprio(0);

        // ---- online softmax with deferred rescale (THR=0)
        float mx[2][4]; bool need = false;
#pragma unroll
        for (int qt = 0; qt < 2; qt++)
#pragma unroll
            for (int r = 0; r < 4; r++) {
                float v = fmaxf(fmaxf(s[qt][0][r], s[qt][1][r]), fmaxf(s[qt][2][r], s[qt][3][r]));
                v = fmaxf(v, __shfl_xor(v, 1));
                v = fmaxf(v, __shfl_xor(v, 2));
                v = fmaxf(v, __shfl_xor(v, 4));
                v = fmaxf(v, __shfl_xor(v, 8));
                mx[qt][r] = v;
                need = need || (v > m_r[qt][r]);
            }
        if (__ballot(need) != 0ull) {
#pragma unroll
            for (int qt = 0; qt < 2; qt++)
#pragma unroll
                for (int r = 0; r < 4; r++) {
                    float mn  = fmaxf(m_r[qt][r], mx[qt][r]);
                    float fac = __expf(m_r[qt][r] - mn);
                    m_r[qt][r] = mn;
                    l_r[qt][r] *= fac;
#pragma unroll
                    for (int ct = 0; ct < 8; ct++) o_acc[qt][ct][r] *= fac;
                }
        }
#pragma unroll
        for (int qt = 0; qt < 2; qt++)
#pragma unroll
            for (int r = 0; r < 4; r++) {
                float m0 = m_r[qt][r], ps = 0.f;
#pragma unroll
                for (int mt = 0; mt < 4; mt++) {
                    float p = __expf(s[qt][mt][r] - m0);
                    s[qt][mt][r] = p; ps += p;
                }
                ps += __shfl_xor(ps, 1);
                ps += __shfl_xor(ps, 2);
                ps += __shfl_xor(ps, 4);
                ps += __shfl_xor(ps, 8);
                l_r[qt][r] += ps;
            }

        // ---- P -> LDS (bf16) [qrow][kv]; wave pairs write identical data
#pragma unroll
        for (int qt = 0; qt < 2; qt++)
#pragma unroll
            for (int mt = 0; mt < 4; mt++)
#pragma unroll
                for (int r = 0; r < 4; r++)
                    P_lds[qw][qt*16 + lg*4 + r][mt*16 + lc] = f2bf(s[qt][mt][r]);

        // ---- O += P V  (own c-half)
        __builtin_amdgcn_s_setprio(1);
#pragma unroll
        for (int kh = 0; kh < 2; kh++) {
            bf16x8 pf0 = *(const bf16x8*)&P_lds[qw][lc][kh*32 + lg*8];
            bf16x8 pf1 = *(const bf16x8*)&P_lds[qw][16 + lc][kh*32 + lg*8];
#pragma unroll
            for (int ct = 0; ct < 8; ct++) {
                int row = (ch*8 + ct)*16 + lc;
                bf16x8 vf = *(const bf16x8*)&V_lds[cur][row][(kh*32 + lg*8) ^ ((lc & 7) << 3)];
                o_acc[0][ct] = MFMA(pf0, vf, o_acc[0][ct], 0, 0, 0);
                o_acc[1][ct] = MFMA(pf1, vf, o_acc[1][ct], 0, 0, 0);
            }
        }
        __builtin_amdgcn_s_setprio(0);
        __syncthreads();
    }

    // ---- epilogue: out[b][c][n] = gamma * O[n][c] / l[n] + kv[b][c][n]
    const float g = gamma_p[0];
    float inv[2][4];
#pragma unroll
    for (int qt = 0; qt < 2; qt++)
#pragma unroll
        for (int r = 0; r < 4; r++) inv[qt][r] = g / l_r[qt][r];

    float* o_tr = (float*)&V_lds[0][0][0];   // [32][132] f32 = 16.9 KB
    for (int cc = 0; cc < 8; cc++) {
        __syncthreads();
        if ((cc >> 2) == ch) {
            int ctb = (cc & 3) * 2;
#pragma unroll
            for (int ci = 0; ci < 2; ci++) {
                int ct = ctb + ci;
#pragma unroll
                for (int qt = 0; qt < 2; qt++)
#pragma unroll
                    for (int r = 0; r < 4; r++)
                        o_tr[(ci*16 + lc)*132 + qw*32 + qt*16 + lg*4 + r] =
                            o_acc[qt][ct][r] * inv[qt][r];
            }
        }
        __syncthreads();
        int c_loc = t >> 4, seg = (t & 15) * 8;
        int c = cc*32 + c_loc;
        size_t base = ((size_t)b * CV_ + c) * N_ + q0 + seg;
        float4 kv1 = *(const float4*)(kvp + base);
        float4 kv2 = *(const float4*)(kvp + base + 4);
        float4 r1, r2;
        r1.x = o_tr[c_loc*132 + seg + 0] + kv1.x;
        r1.y = o_tr[c_loc*132 + seg + 1] + kv1.y;
        r1.z = o_tr[c_loc*132 + seg + 2] + kv1.z;
        r1.w = o_tr[c_loc*132 + seg + 3] + kv1.w;
        r2.x = o_tr[c_loc*132 + seg + 4] + kv2.x;
        r2.y = o_tr[c_loc*132 + seg + 5] + kv2.y;
        r2.z = o_tr[c_loc*132 + seg + 6] + kv2.z;
        r2.w = o_tr[c_loc*132 + seg + 7] + kv2.w;
        *(float4*)(out + base)     = r1;
        *(float4*)(out + base + 4) = r2;
    }
}

extern "C" void kernel_launch(void* const* d_in, const int* in_sizes, int n_in,
                              void* d_out, int out_size, void* d_ws, size_t ws_size,
                              hipStream_t stream)
{
    const float* q     = (const float*)d_in[0];
    const float* kv    = (const float*)d_in[1];
    const float* Wf    = (const float*)d_in[2];
    const float* pbf   = (const float*)d_in[3];
    const float* Wg    = (const float*)d_in[4];
    const float* pbg   = (const float*)d_in[5];
    const float* Wh    = (const float*)d_in[6];
    const float* pbh   = (const float*)d_in[7];
    const float* gamma = (const float*)d_in[8];
    float* out = (float*)d_out;

    // ws layout (u16): wfb 8192 | wgb 8192 | whb 65536 | fbuf 1M | gbuf 1M | hbuf 8M
    u16* wfb  = (u16*)d_ws;
    u16* wgb  = wfb + 8192;
    u16* whb  = wgb + 8192;
    u16* fbuf = whb + 65536;
    u16* gbuf = fbuf + (size_t)B_ * N_ * D_;
    u16* hbuf = gbuf + (size_t)B_ * N_ * D_;

    wcvt_kernel<<<dim3(80), dim3(256), 0, stream>>>(Wf, Wg, Wh, wfb, wgb, whb);
    proj_kernel<<<dim3(512), dim3(512), 0, stream>>>(q, kv, wfb, pbf, wgb, pbg, whb, pbh,
                                                     fbuf, gbuf, hbuf);
    attn_kernel<<<dim3(256), dim3(512), 0, stream>>>(fbuf, gbuf, hbuf, kv, gamma, out);
}

// Round 3
// 205.080 us; speedup vs baseline: 3.5748x; 1.3310x over previous
//
#include <hip/hip_runtime.h>
#include <hip/hip_bf16.h>

typedef unsigned short u16;
typedef unsigned int u32;
typedef __bf16 bf16x8 __attribute__((ext_vector_type(8)));
typedef u16 u16x8 __attribute__((ext_vector_type(8)));
typedef float f32x4 __attribute__((ext_vector_type(4)));
typedef float f32x16 __attribute__((ext_vector_type(16)));

#define B_  8
#define N_  4096
#define D_  32
#define CV_ 256

#define MFMA16 __builtin_amdgcn_mfma_f32_16x16x32_bf16
#define MFMA32 __builtin_amdgcn_mfma_f32_32x32x16_bf16

static __device__ __forceinline__ u16 f2bf(float x) {
    union { float f; unsigned int u; } v; v.f = x;
    unsigned int r = (v.u + 0x7FFFu + ((v.u >> 16) & 1u)) >> 16;
    return (u16)r;
}

static __device__ __forceinline__ void gload16(const u16* g, u16* l) {
    __builtin_amdgcn_global_load_lds(
        (const __attribute__((address_space(1))) unsigned int*)g,
        (__attribute__((address_space(3))) unsigned int*)l, 16, 0, 0);
}

// ---------------- W convert kernel: f32 -> bf16, row-major [out][in] ----------------
__global__ void wcvt_kernel(const float* __restrict__ Wf, const float* __restrict__ Wg,
                            const float* __restrict__ Wh,
                            u16* __restrict__ wfb, u16* __restrict__ wgb, u16* __restrict__ whb)
{
    int i = (blockIdx.x * 256 + threadIdx.x) * 4;   // 81920 f32 total, grid 80x256
    const float* src; u16* dst;
    if (i < 8192)       { src = Wf + i;         dst = wfb + i; }
    else if (i < 16384) { src = Wg + i - 8192;  dst = wgb + i - 8192; }
    else                { src = Wh + i - 16384; dst = whb + i - 16384; }
    float4 v = *(const float4*)src;
    ushort4 o; o.x = f2bf(v.x); o.y = f2bf(v.y); o.z = f2bf(v.z); o.w = f2bf(v.w);
    *(ushort4*)dst = o;
}

// ---------------- projection kernel (MFMA 16x16x32) ----------------
// grid = 512 (b = blk&7, n0 = (blk>>3)*64), 512 threads (8 waves).
// Outputs:
//   fbuf [b][n][32]                          (Q rows, plain)
//   gbuf [b][kt=n>>5][kv=n&31][slot^kv&3][8] (K, kv-tiled + slot-swizzled)
//   hbuf [b][kt][c][slot^(c&3)][8]           (V^T, kv-tiled + slot-swizzled)
__global__ __launch_bounds__(512, 4)
void proj_kernel(const float* __restrict__ q, const float* __restrict__ kv,
                 const u16* __restrict__ wfb, const float* __restrict__ pbf,
                 const u16* __restrict__ wgb, const float* __restrict__ pbg,
                 const u16* __restrict__ whb, const float* __restrict__ pbh,
                 u16* __restrict__ fbuf, u16* __restrict__ gbuf, u16* __restrict__ hbuf)
{
    __shared__ __align__(16) u16 xq[64][256];   // 32 KB
    __shared__ __align__(16) u16 xk[64][256];   // 32 KB
    const int b  = blockIdx.x & 7;
    const int n0 = (blockIdx.x >> 3) * 64;
    const int t  = threadIdx.x;
    const int w  = t >> 6, lane = t & 63, lg = lane >> 4, lc = lane & 15;
    const size_t bb = (size_t)b * CV_ * N_;
    const f32x4 zf = {0.f, 0.f, 0.f, 0.f};

    // ---- stage q,kv tiles transposed -> [n][k] bf16 with chunk swizzle
    {
        int n = t & 63, cg = t >> 6;
        for (int p = 0; p < 16; p++) {
            int c = (p * 8 + cg) * 2;
            const float* qp = q  + bb + (size_t)c * N_ + n0 + n;
            const float* kp = kv + bb + (size_t)c * N_ + n0 + n;
            float q0v = qp[0], q1v = qp[N_];
            float k0v = kp[0], k1v = kp[N_];
            int idx = (((c >> 3) ^ (n & 7)) * 8) + (c & 7);
            *(unsigned*)&xq[n][idx] = (unsigned)f2bf(q0v) | ((unsigned)f2bf(q1v) << 16);
            *(unsigned*)&xk[n][idx] = (unsigned)f2bf(k0v) | ((unsigned)f2bf(k1v) << 16);
        }
    }
    __syncthreads();

    // ---- f (waves 0-3) / g (waves 4-7): per-pixel projections to 32 channels
    {
        const u16*  wsel = (w < 4) ? wfb : wgb;
        const float* bsel = (w < 4) ? pbf : pbg;
        const u16 (*xs)[256] = (w < 4) ? (const u16(*)[256])xq : (const u16(*)[256])xk;
        const int nch = w & 3;
        f32x4 acc[2] = {zf, zf};
#pragma unroll
        for (int kk = 0; kk < 8; kk++) {
            bf16x8 a = *(const bf16x8*)&xs[nch*16 + lc][((kk*4 + lg) ^ (lc & 7)) * 8];
#pragma unroll
            for (int bt = 0; bt < 2; bt++) {
                bf16x8 bw = *(const bf16x8*)&wsel[(size_t)(bt*16 + lc) * 256 + kk*32 + lg*8];
                acc[bt] = MFMA16(a, bw, acc[bt], 0, 0, 0);
            }
        }
        if (w < 4) {
#pragma unroll
            for (int bt = 0; bt < 2; bt++) {
                float bias = bsel[bt*16 + lc];
#pragma unroll
                for (int r = 0; r < 4; r++) {
                    int n = n0 + nch*16 + lg*4 + r;
                    fbuf[((size_t)b * N_ + n) * D_ + bt*16 + lc] = f2bf(acc[bt][r] + bias);
                }
            }
        } else {
#pragma unroll
            for (int bt = 0; bt < 2; bt++) {
                float bias = bsel[bt*16 + lc];
                int dk = bt*16 + lc;
#pragma unroll
                for (int r = 0; r < 4; r++) {
                    int n = n0 + nch*16 + lg*4 + r;
                    size_t off = ((size_t)b*128 + (n>>5))*1024 + (size_t)(n&31)*32
                               + ((((dk>>3)&3) ^ (n&3)) << 3) + (dk&7);
                    gbuf[off] = f2bf(acc[bt][r] + bias);
                }
            }
        }
    }

    // ---- h (all waves): V^T tiled+swizzled, c-stripe = w*32
    {
        const int cw = w * 32;
        f32x4 acch[2][4];
#pragma unroll
        for (int ct = 0; ct < 2; ct++)
#pragma unroll
            for (int nt = 0; nt < 4; nt++) acch[ct][nt] = zf;
#pragma unroll
        for (int kk = 0; kk < 8; kk++) {
            bf16x8 ah[2];
#pragma unroll
            for (int ct = 0; ct < 2; ct++)
                ah[ct] = *(const bf16x8*)&whb[(size_t)(cw + ct*16 + lc) * 256 + kk*32 + lg*8];
#pragma unroll
            for (int nt = 0; nt < 4; nt++) {
                bf16x8 bx = *(const bf16x8*)&xk[nt*16 + lc][((kk*4 + lg) ^ (lc & 7)) * 8];
#pragma unroll
                for (int ct = 0; ct < 2; ct++)
                    acch[ct][nt] = MFMA16(ah[ct], bx, acch[ct][nt], 0, 0, 0);
            }
        }
#pragma unroll
        for (int ct = 0; ct < 2; ct++)
#pragma unroll
            for (int r = 0; r < 4; r++) {
                int c = cw + ct*16 + lg*4 + r;
                float bias = pbh[c];
#pragma unroll
                for (int nt = 0; nt < 4; nt++) {
                    int n = n0 + nt*16 + lc;
                    size_t off = ((size_t)b*128 + (n>>5))*8192 + (size_t)c*32
                               + ((((n>>3)&3) ^ (c&3)) << 3) + (n&7);
                    hbuf[off] = f2bf(acch[ct][nt][r] + bias);
                }
            }
    }
}

// ---------------- flash attention kernel (32x32 MFMA, swapped QK^T) ----------------
// grid 256 (b = blk&7, q0 = (blk>>3)*128), 512 threads = 8 waves.
// wave: qw = w&3 (32 q-rows), ch = w>>2 (c-half: 4 ct of 32). KVB=32, 128 tiles, dbuf.
__global__ __launch_bounds__(512, 2)
void attn_kernel(const u16* __restrict__ fbuf, const u16* __restrict__ gbuf,
                 const u16* __restrict__ hbuf, const float* __restrict__ kvp,
                 const float* __restrict__ gamma_p, float* __restrict__ out)
{
    __shared__ __align__(16) u16 smem[2*8192 + 2*1024];   // V dbuf 32KB | K dbuf 4KB

    const int b  = blockIdx.x & 7;
    const int q0 = (blockIdx.x >> 3) * 128;
    const int t  = threadIdx.x;
    const int w  = t >> 6;
    const int l  = t & 63;
    const int qw = w & 3;
    const int ch = w >> 2;
    const int lr = l & 31;
    const int b5 = l >> 5;
    const int r3 = l & 3;

    const u16* hb_t = hbuf + (size_t)b * 128 * 8192;
    const u16* gb_t = gbuf + (size_t)b * 128 * 1024;

    // Q B-fragments (q-col = lr, dk chunks kq=0,1)
    bf16x8 qf0, qf1;
    {
        const u16* fb = fbuf + ((size_t)b * N_ + q0 + qw*32 + lr) * D_;
        qf0 = *(const bf16x8*)(fb + b5*8);
        qf1 = *(const bf16x8*)(fb + 16 + b5*8);
    }

    const f32x16 zf16 = {0,0,0,0, 0,0,0,0, 0,0,0,0, 0,0,0,0};
    f32x16 o_acc[4] = {zf16, zf16, zf16, zf16};
    float m_r = -1e30f, l_r = 0.f;

    // per-lane LDS element offsets (slot-XOR swizzle baked into gbuf/hbuf)
    const int koff0 = lr*32 + (((0|b5) ^ r3) << 3);
    const int koff1 = lr*32 + (((2|b5) ^ r3) << 3);
    const int vbase = (ch*128 + lr)*32;
    const int vph0  = ((0|b5) ^ r3) << 3;
    const int vph1  = ((2|b5) ^ r3) << 3;

    auto stage = [&](int nb, int kt) {
        const u16* sv = hb_t + (size_t)kt*8192 + t*8;
        u16* dv = smem + nb*8192 + t*8;
        gload16(sv, dv);
        gload16(sv + 4096, dv + 4096);
        if (t < 128)
            gload16(gb_t + (size_t)kt*1024 + t*8, smem + 16384 + nb*1024 + t*8);
    };

    stage(0, 0);

    for (int kt = 0; kt < 128; ++kt) {
        const int cur = kt & 1;
        __syncthreads();                      // drains vmcnt -> tile kt staged, prev readers done
        if (kt < 127) stage(cur ^ 1, kt + 1);

        const u16* Kl = smem + 16384 + cur*1024;
        const u16* Vl = smem + cur*8192;

        // ---- S = K·Q (swapped): lane holds P-logits[q=lr][kv = r+8g+4*b5]
        bf16x8 kf0 = *(const bf16x8*)(Kl + koff0);
        bf16x8 kf1 = *(const bf16x8*)(Kl + koff1);
        f32x16 s = MFMA32(kf0, qf0, zf16, 0, 0, 0);
        s = MFMA32(kf1, qf1, s, 0, 0, 0);

        // ---- online softmax, row = lane-local + one xor32 reduce
        float pmax = s[0];
#pragma unroll
        for (int i = 1; i < 16; ++i) pmax = fmaxf(pmax, s[i]);
        pmax = fmaxf(pmax, __shfl_xor(pmax, 32));

        bool need = pmax > m_r + 8.0f;        // deferred-max THR=8
        if (__ballot(need)) {
            float mn  = fmaxf(m_r, pmax);
            float fac = __expf(m_r - mn);
            m_r = mn;
            l_r *= fac;
#pragma unroll
            for (int g = 0; g < 16; ++g) {
                int qp = (g & 3) + 8*(g >> 2) + b5*4;
                float fr = __shfl(fac, qp);
                o_acc[0][g] *= fr; o_acc[1][g] *= fr;
                o_acc[2][g] *= fr; o_acc[3][g] *= fr;
            }
        }
        float psum = 0.f;
#pragma unroll
        for (int i = 0; i < 16; ++i) {
            float p = __expf(s[i] - m_r);
            s[i] = p;
            psum += p;
        }
        psum += __shfl_xor(psum, 32);
        l_r += psum;

        // ---- pack P (bf16) + xor32 exchange -> PV A-fragments
        bf16x8 pa[2];
#pragma unroll
        for (int kc = 0; kc < 2; ++kc) {
            u32 d0, d1, e0, e1;
            { __hip_bfloat162 h = __float22bfloat162_rn(make_float2(s[8*kc+0], s[8*kc+1])); d0 = *(u32*)&h; }
            { __hip_bfloat162 h = __float22bfloat162_rn(make_float2(s[8*kc+2], s[8*kc+3])); d1 = *(u32*)&h; }
            { __hip_bfloat162 h = __float22bfloat162_rn(make_float2(s[8*kc+4], s[8*kc+5])); e0 = *(u32*)&h; }
            { __hip_bfloat162 h = __float22bfloat162_rn(make_float2(s[8*kc+6], s[8*kc+7])); e1 = *(u32*)&h; }
            u32 rd0 = __shfl_xor(d0, 32), rd1 = __shfl_xor(d1, 32);
            u32 re0 = __shfl_xor(e0, 32), re1 = __shfl_xor(e1, 32);
            union { u32 u[4]; bf16x8 v; } pk;
            pk.u[0] = b5 ? re0 : d0;
            pk.u[1] = b5 ? re1 : d1;
            pk.u[2] = b5 ? e0  : rd0;
            pk.u[3] = b5 ? e1  : rd1;
            pa[kc] = pk.v;
        }

        // ---- O += P·V on own c-half (4 ct of 32 cols)
        __builtin_amdgcn_s_setprio(1);
#pragma unroll
        for (int ct = 0; ct < 4; ++ct) {
            bf16x8 v0 = *(const bf16x8*)(Vl + vbase + ct*1024 + vph0);
            bf16x8 v1 = *(const bf16x8*)(Vl + vbase + ct*1024 + vph1);
            o_acc[ct] = MFMA32(pa[0], v0, o_acc[ct], 0, 0, 0);
            o_acc[ct] = MFMA32(pa[1], v1, o_acc[ct], 0, 0, 0);
        }
        __builtin_amdgcn_s_setprio(0);
    }

    // ---- epilogue: out[b][c][n] = gamma * O[n][c] / l[n] + kv[b][c][n]
    const float gmm = gamma_p[0];
    float linv[16];
#pragma unroll
    for (int g = 0; g < 16; ++g) {
        int qp = (g & 3) + 8*(g >> 2) + b5*4;
        float lv = __shfl(l_r, qp);
        linv[g] = gmm / lv;
    }

    float* o_tr = (float*)smem;   // [64][132] f32 = 33792 B
    for (int cc = 0; cc < 4; ++cc) {
        __syncthreads();
        if (ch == (cc >> 1)) {
#pragma unroll
            for (int ci = 0; ci < 2; ++ci) {
                int ct = (cc & 1)*2 + ci;
#pragma unroll
                for (int g = 0; g < 16; ++g) {
                    int q_loc = (g & 3) + 8*(g >> 2) + b5*4;
                    o_tr[(ci*32 + lr)*132 + qw*32 + q_loc] = o_acc[ct][g] * linv[g];
                }
            }
        }
        __syncthreads();
        int c_loc = t >> 3, j = t & 7;
        int c = cc*64 + c_loc;
        size_t base = ((size_t)b*CV_ + c)*N_ + q0 + j*16;
        const float* orow = o_tr + c_loc*132 + j*16;
#pragma unroll
        for (int u = 0; u < 4; ++u) {
            float4 kvv = *(const float4*)(kvp + base + u*4);
            float4 rs;
            rs.x = orow[u*4+0] + kvv.x;
            rs.y = orow[u*4+1] + kvv.y;
            rs.z = orow[u*4+2] + kvv.z;
            rs.w = orow[u*4+3] + kvv.w;
            *(float4*)(out + base + u*4) = rs;
        }
    }
}

extern "C" void kernel_launch(void* const* d_in, const int* in_sizes, int n_in,
                              void* d_out, int out_size, void* d_ws, size_t ws_size,
                              hipStream_t stream)
{
    const float* q     = (const float*)d_in[0];
    const float* kv    = (const float*)d_in[1];
    const float* Wf    = (const float*)d_in[2];
    const float* pbf   = (const float*)d_in[3];
    const float* Wg    = (const float*)d_in[4];
    const float* pbg   = (const float*)d_in[5];
    const float* Wh    = (const float*)d_in[6];
    const float* pbh   = (const float*)d_in[7];
    const float* gamma = (const float*)d_in[8];
    float* out = (float*)d_out;

    // ws layout (u16): wfb 8192 | wgb 8192 | whb 65536 | fbuf 1M | gbuf 1M | hbuf 8M
    u16* wfb  = (u16*)d_ws;
    u16* wgb  = wfb + 8192;
    u16* whb  = wgb + 8192;
    u16* fbuf = whb + 65536;
    u16* gbuf = fbuf + (size_t)B_ * N_ * D_;
    u16* hbuf = gbuf + (size_t)B_ * N_ * D_;

    wcvt_kernel<<<dim3(80), dim3(256), 0, stream>>>(Wf, Wg, Wh, wfb, wgb, whb);
    proj_kernel<<<dim3(512), dim3(512), 0, stream>>>(q, kv, wfb, pbf, wgb, pbg, whb, pbh,
                                                     fbuf, gbuf, hbuf);
    attn_kernel<<<dim3(256), dim3(512), 0, stream>>>(fbuf, gbuf, hbuf, kv, gamma, out);
}

// Round 4
// 167.932 us; speedup vs baseline: 4.3656x; 1.2212x over previous
//
#include <hip/hip_runtime.h>
#include <hip/hip_bf16.h>

typedef unsigned short u16;
typedef unsigned int u32;
typedef __bf16 bf16x8 __attribute__((ext_vector_type(8)));
typedef float f32x4 __attribute__((ext_vector_type(4)));
typedef float f32x16 __attribute__((ext_vector_type(16)));

#define B_  8
#define N_  4096
#define D_  32
#define CV_ 256

#define MFMA16 __builtin_amdgcn_mfma_f32_16x16x32_bf16
#define MFMA32 __builtin_amdgcn_mfma_f32_32x32x16_bf16

static __device__ __forceinline__ u16 f2bf(float x) {
    union { float f; unsigned int u; } v; v.f = x;
    unsigned int r = (v.u + 0x7FFFu + ((v.u >> 16) & 1u)) >> 16;
    return (u16)r;
}

static __device__ __forceinline__ void gload16(const u16* g, u16* l) {
    __builtin_amdgcn_global_load_lds(
        (const __attribute__((address_space(1))) unsigned int*)g,
        (__attribute__((address_space(3))) unsigned int*)l, 16, 0, 0);
}

// ---------------- W convert kernel ----------------
__global__ void wcvt_kernel(const float* __restrict__ Wf, const float* __restrict__ Wg,
                            const float* __restrict__ Wh,
                            u16* __restrict__ wfb, u16* __restrict__ wgb, u16* __restrict__ whb)
{
    int i = (blockIdx.x * 256 + threadIdx.x) * 4;
    const float* src; u16* dst;
    if (i < 8192)       { src = Wf + i;         dst = wfb + i; }
    else if (i < 16384) { src = Wg + i - 8192;  dst = wgb + i - 8192; }
    else                { src = Wh + i - 16384; dst = whb + i - 16384; }
    float4 v = *(const float4*)src;
    ushort4 o; o.x = f2bf(v.x); o.y = f2bf(v.y); o.z = f2bf(v.z); o.w = f2bf(v.w);
    *(ushort4*)dst = o;
}

// ---------------- projection kernel (MFMA 16x16x32) ----------------
// Outputs:
//   fbuf [b][n][32]                              (Q rows, plain)
//   gbuf [b][kt][kv][slot^((kv>>1)&3)][8]        (K, kv-tiled, batch-spread swizzle)
//   hbuf [b][kt][c][slot^((c>>1)&3)][8]          (V^T, kv-tiled, batch-spread swizzle)
__global__ __launch_bounds__(512, 4)
void proj_kernel(const float* __restrict__ q, const float* __restrict__ kv,
                 const u16* __restrict__ wfb, const float* __restrict__ pbf,
                 const u16* __restrict__ wgb, const float* __restrict__ pbg,
                 const u16* __restrict__ whb, const float* __restrict__ pbh,
                 u16* __restrict__ fbuf, u16* __restrict__ gbuf, u16* __restrict__ hbuf)
{
    __shared__ __align__(16) u16 xq[64][256];
    __shared__ __align__(16) u16 xk[64][256];
    const int b  = blockIdx.x & 7;
    const int n0 = (blockIdx.x >> 3) * 64;
    const int t  = threadIdx.x;
    const int w  = t >> 6, lane = t & 63, lg = lane >> 4, lc = lane & 15;
    const size_t bb = (size_t)b * CV_ * N_;
    const f32x4 zf = {0.f, 0.f, 0.f, 0.f};

    {
        int n = t & 63, cg = t >> 6;
        for (int p = 0; p < 16; p++) {
            int c = (p * 8 + cg) * 2;
            const float* qp = q  + bb + (size_t)c * N_ + n0 + n;
            const float* kp = kv + bb + (size_t)c * N_ + n0 + n;
            float q0v = qp[0], q1v = qp[N_];
            float k0v = kp[0], k1v = kp[N_];
            int idx = (((c >> 3) ^ (n & 7)) * 8) + (c & 7);
            *(unsigned*)&xq[n][idx] = (unsigned)f2bf(q0v) | ((unsigned)f2bf(q1v) << 16);
            *(unsigned*)&xk[n][idx] = (unsigned)f2bf(k0v) | ((unsigned)f2bf(k1v) << 16);
        }
    }
    __syncthreads();

    {
        const u16*  wsel = (w < 4) ? wfb : wgb;
        const float* bsel = (w < 4) ? pbf : pbg;
        const u16 (*xs)[256] = (w < 4) ? (const u16(*)[256])xq : (const u16(*)[256])xk;
        const int nch = w & 3;
        f32x4 acc[2] = {zf, zf};
#pragma unroll
        for (int kk = 0; kk < 8; kk++) {
            bf16x8 a = *(const bf16x8*)&xs[nch*16 + lc][((kk*4 + lg) ^ (lc & 7)) * 8];
#pragma unroll
            for (int bt = 0; bt < 2; bt++) {
                bf16x8 bw = *(const bf16x8*)&wsel[(size_t)(bt*16 + lc) * 256 + kk*32 + lg*8];
                acc[bt] = MFMA16(a, bw, acc[bt], 0, 0, 0);
            }
        }
        if (w < 4) {
#pragma unroll
            for (int bt = 0; bt < 2; bt++) {
                float bias = bsel[bt*16 + lc];
#pragma unroll
                for (int r = 0; r < 4; r++) {
                    int n = n0 + nch*16 + lg*4 + r;
                    fbuf[((size_t)b * N_ + n) * D_ + bt*16 + lc] = f2bf(acc[bt][r] + bias);
                }
            }
        } else {
#pragma unroll
            for (int bt = 0; bt < 2; bt++) {
                float bias = bsel[bt*16 + lc];
                int dk = bt*16 + lc;
#pragma unroll
                for (int r = 0; r < 4; r++) {
                    int n = n0 + nch*16 + lg*4 + r;
                    size_t off = ((size_t)b*128 + (n>>5))*1024 + (size_t)(n&31)*32
                               + ((((dk>>3)&3) ^ ((n>>1)&3)) << 3) + (dk&7);
                    gbuf[off] = f2bf(acc[bt][r] + bias);
                }
            }
        }
    }

    {
        const int cw = w * 32;
        f32x4 acch[2][4];
#pragma unroll
        for (int ct = 0; ct < 2; ct++)
#pragma unroll
            for (int nt = 0; nt < 4; nt++) acch[ct][nt] = zf;
#pragma unroll
        for (int kk = 0; kk < 8; kk++) {
            bf16x8 ah[2];
#pragma unroll
            for (int ct = 0; ct < 2; ct++)
                ah[ct] = *(const bf16x8*)&whb[(size_t)(cw + ct*16 + lc) * 256 + kk*32 + lg*8];
#pragma unroll
            for (int nt = 0; nt < 4; nt++) {
                bf16x8 bx = *(const bf16x8*)&xk[nt*16 + lc][((kk*4 + lg) ^ (lc & 7)) * 8];
#pragma unroll
                for (int ct = 0; ct < 2; ct++)
                    acch[ct][nt] = MFMA16(ah[ct], bx, acch[ct][nt], 0, 0, 0);
            }
        }
#pragma unroll
        for (int ct = 0; ct < 2; ct++)
#pragma unroll
            for (int r = 0; r < 4; r++) {
                int c = cw + ct*16 + lg*4 + r;
                float bias = pbh[c];
#pragma unroll
                for (int nt = 0; nt < 4; nt++) {
                    int n = n0 + nt*16 + lc;
                    size_t off = ((size_t)b*128 + (n>>5))*8192 + (size_t)c*32
                               + ((((n>>3)&3) ^ ((c>>1)&3)) << 3) + (n&7);
                    hbuf[off] = f2bf(acch[ct][nt][r] + bias);
                }
            }
    }
}

// ---------------- flash attention kernel (32x32 MFMA, swapped QK^T) ----------------
// grid 256 (b = blk&7, q0 = (blk>>3)*128), 512 threads = 8 waves.
// 4 LDS buffers, 2-tile-deep prefetch, barrier every 2 tiles.
__global__ __launch_bounds__(512, 2)
void attn_kernel(const u16* __restrict__ fbuf, const u16* __restrict__ gbuf,
                 const u16* __restrict__ hbuf, const float* __restrict__ kvp,
                 const float* __restrict__ gamma_p, float* __restrict__ out)
{
    __shared__ __align__(16) u16 smem[4 * 9216];   // 4 x (V 16KB + K 2KB) = 72 KB

    const int b  = blockIdx.x & 7;
    const int q0 = (blockIdx.x >> 3) * 128;
    const int t  = threadIdx.x;
    const int w  = t >> 6;
    const int l  = t & 63;
    const int qw = w & 3;
    const int ch = w >> 2;
    const int lr = l & 31;
    const int b5 = l >> 5;
    const int sw = (lr >> 1) & 3;          // batch-spread swizzle term

    const u16* hb_t = hbuf + (size_t)b * 128 * 8192;
    const u16* gb_t = gbuf + (size_t)b * 128 * 1024;

    bf16x8 qf0, qf1;
    {
        const u16* fb = fbuf + ((size_t)b * N_ + q0 + qw*32 + lr) * D_;
        qf0 = *(const bf16x8*)(fb + b5*8);
        qf1 = *(const bf16x8*)(fb + 16 + b5*8);
    }

    const f32x16 zf16 = {0,0,0,0, 0,0,0,0, 0,0,0,0, 0,0,0,0};
    f32x16 o_acc[4] = {zf16, zf16, zf16, zf16};
    float m_r = -1e30f, l_r = 0.f;

    const int koff0 = lr*32 + (((0|b5) ^ sw) << 3);
    const int koff1 = lr*32 + (((2|b5) ^ sw) << 3);
    const int vbase = (ch*128 + lr)*32;
    const int vph0  = ((0|b5) ^ sw) << 3;
    const int vph1  = ((2|b5) ^ sw) << 3;

    auto stage = [&](int nb, int kt) {
        const u16* sv = hb_t + (size_t)kt*8192 + t*8;
        u16* dv = smem + nb*9216 + t*8;
        gload16(sv, dv);
        gload16(sv + 4096, dv + 4096);
        if (t < 128)
            gload16(gb_t + (size_t)kt*1024 + t*8, smem + nb*9216 + 8192 + t*8);
    };

    stage(0, 0); stage(1, 1);

    for (int p = 0; p < 64; ++p) {
        __syncthreads();                         // drains vmcnt: tiles 2p,2p+1 staged
        if (p < 63) { stage((2*p+2)&3, 2*p+2); stage((2*p+3)&3, 2*p+3); }

#pragma unroll
        for (int sub = 0; sub < 2; ++sub) {
            const int nb = (2*p + sub) & 3;
            const u16* Kl = smem + nb*9216 + 8192;
            const u16* Vl = smem + nb*9216;

            bf16x8 kf0 = *(const bf16x8*)(Kl + koff0);
            bf16x8 kf1 = *(const bf16x8*)(Kl + koff1);
            __builtin_amdgcn_s_setprio(1);
            f32x16 s = MFMA32(kf0, qf0, zf16, 0, 0, 0);
            s = MFMA32(kf1, qf1, s, 0, 0, 0);
            __builtin_amdgcn_s_setprio(0);

            // ---- online softmax (lane-local rows + permlane cross-half reduce)
            float pmax = s[0];
#pragma unroll
            for (int i = 1; i < 16; ++i) pmax = fmaxf(pmax, s[i]);
            { float a = pmax, bb2 = pmax;
              asm("v_permlane32_swap_b32 %0, %1" : "+v"(a), "+v"(bb2));
              pmax = fmaxf(a, bb2); }

            bool need = pmax > m_r + 8.0f;       // deferred-max THR=8
            if (__ballot(need)) {
                float mn  = fmaxf(m_r, pmax);
                float fac = __expf(m_r - mn);
                m_r = mn;
                l_r *= fac;
#pragma unroll
                for (int g = 0; g < 16; ++g) {
                    int qp = (g & 3) + 8*(g >> 2) + b5*4;
                    float fr = __shfl(fac, qp);
                    o_acc[0][g] *= fr; o_acc[1][g] *= fr;
                    o_acc[2][g] *= fr; o_acc[3][g] *= fr;
                }
            }
            float psum = 0.f;
#pragma unroll
            for (int i = 0; i < 16; ++i) {
                float pv = __expf(s[i] - m_r);
                s[i] = pv;
                psum += pv;
            }
            { float a = psum, bb2 = psum;
              asm("v_permlane32_swap_b32 %0, %1" : "+v"(a), "+v"(bb2));
              psum = a + bb2; }
            l_r += psum;

            // ---- pack P -> bf16 A-fragments via permlane32_swap
            bf16x8 pa[2];
#pragma unroll
            for (int kc = 0; kc < 2; ++kc) {
                u32 d0, d1, e0, e1;
                { __hip_bfloat162 h2 = __float22bfloat162_rn(make_float2(s[8*kc+0], s[8*kc+1])); d0 = *(u32*)&h2; }
                { __hip_bfloat162 h2 = __float22bfloat162_rn(make_float2(s[8*kc+2], s[8*kc+3])); d1 = *(u32*)&h2; }
                { __hip_bfloat162 h2 = __float22bfloat162_rn(make_float2(s[8*kc+4], s[8*kc+5])); e0 = *(u32*)&h2; }
                { __hip_bfloat162 h2 = __float22bfloat162_rn(make_float2(s[8*kc+6], s[8*kc+7])); e1 = *(u32*)&h2; }
                asm("v_permlane32_swap_b32 %0, %1" : "+v"(d0), "+v"(e0));
                asm("v_permlane32_swap_b32 %0, %1" : "+v"(d1), "+v"(e1));
                union { u32 u[4]; bf16x8 v; } pk;
                pk.u[0] = d0; pk.u[1] = d1; pk.u[2] = e0; pk.u[3] = e1;
                pa[kc] = pk.v;
            }

            // ---- O += P·V on own c-half
            __builtin_amdgcn_s_setprio(1);
#pragma unroll
            for (int ct = 0; ct < 4; ++ct) {
                bf16x8 v0 = *(const bf16x8*)(Vl + vbase + ct*1024 + vph0);
                bf16x8 v1 = *(const bf16x8*)(Vl + vbase + ct*1024 + vph1);
                o_acc[ct] = MFMA32(pa[0], v0, o_acc[ct], 0, 0, 0);
                o_acc[ct] = MFMA32(pa[1], v1, o_acc[ct], 0, 0, 0);
            }
            __builtin_amdgcn_s_setprio(0);
        }
    }

    // ---- epilogue
    const float gmm = gamma_p[0];
    float linv[16];
#pragma unroll
    for (int g = 0; g < 16; ++g) {
        int qp = (g & 3) + 8*(g >> 2) + b5*4;
        float lv = __shfl(l_r, qp);
        linv[g] = gmm / lv;
    }

    float* o_tr = (float*)smem;   // [64][132] f32 = 33792 B
    for (int cc = 0; cc < 4; ++cc) {
        __syncthreads();
        if (ch == (cc >> 1)) {
#pragma unroll
            for (int ci = 0; ci < 2; ++ci) {
                int ct = (cc & 1)*2 + ci;
#pragma unroll
                for (int g = 0; g < 16; ++g) {
                    int q_loc = (g & 3) + 8*(g >> 2) + b5*4;
                    o_tr[(ci*32 + lr)*132 + qw*32 + q_loc] = o_acc[ct][g] * linv[g];
                }
            }
        }
        __syncthreads();
        int c_loc = t >> 3, j = t & 7;
        int c = cc*64 + c_loc;
        size_t base = ((size_t)b*CV_ + c)*N_ + q0 + j*16;
        const float* orow = o_tr + c_loc*132 + j*16;
#pragma unroll
        for (int u = 0; u < 4; ++u) {
            float4 kvv = *(const float4*)(kvp + base + u*4);
            float4 rs;
            rs.x = orow[u*4+0] + kvv.x;
            rs.y = orow[u*4+1] + kvv.y;
            rs.z = orow[u*4+2] + kvv.z;
            rs.w = orow[u*4+3] + kvv.w;
            *(float4*)(out + base + u*4) = rs;
        }
    }
}

extern "C" void kernel_launch(void* const* d_in, const int* in_sizes, int n_in,
                              void* d_out, int out_size, void* d_ws, size_t ws_size,
                              hipStream_t stream)
{
    const float* q     = (const float*)d_in[0];
    const float* kv    = (const float*)d_in[1];
    const float* Wf    = (const float*)d_in[2];
    const float* pbf   = (const float*)d_in[3];
    const float* Wg    = (const float*)d_in[4];
    const float* pbg   = (const float*)d_in[5];
    const float* Wh    = (const float*)d_in[6];
    const float* pbh   = (const float*)d_in[7];
    const float* gamma = (const float*)d_in[8];
    float* out = (float*)d_out;

    u16* wfb  = (u16*)d_ws;
    u16* wgb  = wfb + 8192;
    u16* whb  = wgb + 8192;
    u16* fbuf = whb + 65536;
    u16* gbuf = fbuf + (size_t)B_ * N_ * D_;
    u16* hbuf = gbuf + (size_t)B_ * N_ * D_;

    wcvt_kernel<<<dim3(80), dim3(256), 0, stream>>>(Wf, Wg, Wh, wfb, wgb, whb);
    proj_kernel<<<dim3(512), dim3(512), 0, stream>>>(q, kv, wfb, pbf, wgb, pbg, whb, pbh,
                                                     fbuf, gbuf, hbuf);
    attn_kernel<<<dim3(256), dim3(512), 0, stream>>>(fbuf, gbuf, hbuf, kv, gamma, out);
}